// Round 1
// baseline (2027.952 us; speedup 1.0000x reference)
//
#include <hip/hip_runtime.h>
#include <math.h>

// =====================================================================
// GraphTransformerLayer: fp32 baseline
//   N=100000 nodes, E=1600000 edges, D=128, H=8, DH=16, DFF=256
// Phases:
//   1) Q,K,V = h @ Wq/Wk/Wv              (gemm128)
//   2) edge: score=exp(clip(K[s].Q[d]/4)); atomics into wV[dst], z[dst]
//   3) X = LN1(h + (wV/z) @ Wo + bo)     (gemm128, fused norm+resid+LN)
//   4) T = relu(X @ W1 + b1)             (gemm128, 2 col tiles)
//   5) out = LN2(X + T @ W2 + b2)        (gemm128 K=256, fused)
// =====================================================================

// ---------------- GEMM: 32-row x 128-col tile per block, 256 threads,
// 4x4 register tile per thread. Optional fused: attn-normalize on A load,
// bias, residual, ReLU, LayerNorm (needs full 128-col rows -> gridDim.y==1).
template<int K, bool ATTNNORM, bool RELU, bool LN, bool RESID, bool BIAS>
__global__ __launch_bounds__(256)
void gemm128(const float* __restrict__ A, const float* __restrict__ zvec,
             const float* __restrict__ B, int ldb,
             const float* __restrict__ bias, const float* __restrict__ resid,
             const float* __restrict__ lng, const float* __restrict__ lnb,
             float* __restrict__ C, int ldc)
{
    __shared__ float as[32 * K];
    __shared__ float bs[64 * 128];
    __shared__ float mean_s[32];
    __shared__ float rs_s[32];

    const int tid  = threadIdx.x;
    const int row0 = blockIdx.x * 32;
    const int col0 = blockIdx.y * 128;

    // ---- stage A tile (32 x K), optionally h_attn = wV / (z + 1e-6)
    {
        const float4* A4  = (const float4*)(A + (size_t)row0 * K);
        float4*       as4 = (float4*)as;
        const int nf4 = 32 * K / 4;
        for (int i = tid; i < nf4; i += 256) {
            float4 v = A4[i];
            if (ATTNNORM) {
                int r  = i / (K / 4);
                int k4 = i % (K / 4);
                float zz  = zvec[(size_t)(row0 + r) * 8 + ((k4 * 4) >> 4)] + 1e-6f;
                float inv = 1.0f / zz;
                v.x *= inv; v.y *= inv; v.z *= inv; v.w *= inv;
            }
            as4[i] = v;
        }
    }

    const int colt = tid & 31;   // 32 col-threads, 4 cols each
    const int rowt = tid >> 5;   // 8 row-threads, 4 rows each
    float acc[4][4] = {{0.f}};

    for (int kc = 0; kc < K; kc += 64) {
        __syncthreads();
        // ---- stage B chunk (64 x 128)
        {
            float4* bs4 = (float4*)bs;
            for (int i = tid; i < 2048; i += 256) {
                int r  = i >> 5;
                int c4 = i & 31;
                bs4[i] = *(const float4*)&B[(size_t)(kc + r) * ldb + col0 + c4 * 4];
            }
        }
        __syncthreads();
        for (int k = 0; k < 64; k += 4) {
            float4 a4[4];
            #pragma unroll
            for (int i = 0; i < 4; ++i)
                a4[i] = *(const float4*)&as[(rowt * 4 + i) * K + kc + k];
            #pragma unroll
            for (int kk = 0; kk < 4; ++kk) {
                float4 b4 = *(const float4*)&bs[(k + kk) * 128 + colt * 4];
                #pragma unroll
                for (int i = 0; i < 4; ++i) {
                    float a = ((const float*)&a4[i])[kk];
                    acc[i][0] += a * b4.x;
                    acc[i][1] += a * b4.y;
                    acc[i][2] += a * b4.z;
                    acc[i][3] += a * b4.w;
                }
            }
        }
    }

    // ---- epilogue
    float4 bv = make_float4(0.f, 0.f, 0.f, 0.f);
    if (BIAS) bv = *(const float4*)&bias[col0 + colt * 4];

    float4 vals[4];
    #pragma unroll
    for (int i = 0; i < 4; ++i) {
        float4 v;
        v.x = acc[i][0] + bv.x;
        v.y = acc[i][1] + bv.y;
        v.z = acc[i][2] + bv.z;
        v.w = acc[i][3] + bv.w;
        if (RESID) {
            const float4 rv = *(const float4*)&resid[(size_t)(row0 + rowt * 4 + i) * 128 + colt * 4];
            v.x += rv.x; v.y += rv.y; v.z += rv.z; v.w += rv.w;
        }
        if (RELU) {
            v.x = fmaxf(v.x, 0.f); v.y = fmaxf(v.y, 0.f);
            v.z = fmaxf(v.z, 0.f); v.w = fmaxf(v.w, 0.f);
        }
        vals[i] = v;
    }

    if (!LN) {
        #pragma unroll
        for (int i = 0; i < 4; ++i)
            *(float4*)&C[(size_t)(row0 + rowt * 4 + i) * ldc + col0 + colt * 4] = vals[i];
        return;
    }

    // ---- fused LayerNorm over the 128-col row (gridDim.y == 1 only)
    float* cs = bs;               // reuse B staging LDS: 32 x 132 (padded)
    __syncthreads();              // everyone done reading bs
    #pragma unroll
    for (int i = 0; i < 4; ++i)
        *(float4*)&cs[(rowt * 4 + i) * 132 + colt * 4] = vals[i];
    __syncthreads();

    {
        const int r   = tid >> 3;   // 32 rows x 8 segs
        const int seg = tid & 7;
        const float4* rp = (const float4*)&cs[r * 132 + seg * 16];
        float s = 0.f, sq = 0.f;
        #pragma unroll
        for (int q = 0; q < 4; ++q) {
            float4 v = rp[q];
            s  += v.x + v.y + v.z + v.w;
            sq += v.x * v.x + v.y * v.y + v.z * v.z + v.w * v.w;
        }
        s  += __shfl_xor(s, 1);  s  += __shfl_xor(s, 2);  s  += __shfl_xor(s, 4);
        sq += __shfl_xor(sq, 1); sq += __shfl_xor(sq, 2); sq += __shfl_xor(sq, 4);
        if (seg == 0) {
            float m = s * (1.f / 128.f);
            mean_s[r] = m;
            rs_s[r]   = rsqrtf(sq * (1.f / 128.f) - m * m + 1e-5f);
        }
    }
    __syncthreads();

    const float4 g4 = *(const float4*)&lng[colt * 4];
    const float4 o4 = *(const float4*)&lnb[colt * 4];
    #pragma unroll
    for (int i = 0; i < 4; ++i) {
        const int r = rowt * 4 + i;
        const float m  = mean_s[r];
        const float rs = rs_s[r];
        float4 v = vals[i];
        v.x = (v.x - m) * rs * g4.x + o4.x;
        v.y = (v.y - m) * rs * g4.y + o4.y;
        v.z = (v.z - m) * rs * g4.z + o4.z;
        v.w = (v.w - m) * rs * g4.w + o4.w;
        *(float4*)&C[(size_t)(row0 + r) * ldc + colt * 4] = v;
    }
}

// ---------------- edge kernel: one wave (64 lanes) per edge ----------------
__global__ __launch_bounds__(256)
void edge_kernel(const float* __restrict__ Q, const float* __restrict__ Km,
                 const float* __restrict__ V, const int* __restrict__ src,
                 const int* __restrict__ dst,
                 float* __restrict__ wV, float* __restrict__ z, int nE)
{
    const int lane = threadIdx.x & 63;
    const int wid  = threadIdx.x >> 6;
    const int e    = blockIdx.x * 4 + wid;
    if (e >= nE) return;

    const int s = src[e];
    const int d = dst[e];

    const float2 kv = *(const float2*)&Km[(size_t)s * 128 + lane * 2];
    const float2 qv = *(const float2*)&Q [(size_t)d * 128 + lane * 2];
    const float2 vv = *(const float2*)&V [(size_t)s * 128 + lane * 2];

    // per-head (16 elems = 8 lanes) dot product
    float p = kv.x * qv.x + kv.y * qv.y;
    p += __shfl_xor(p, 1);
    p += __shfl_xor(p, 2);
    p += __shfl_xor(p, 4);

    float sc = p * 0.25f;                      // / sqrt(16)
    sc = fminf(5.f, fmaxf(-5.f, sc));
    const float se = expf(sc);

    atomicAdd(&wV[(size_t)d * 128 + lane * 2],     vv.x * se);
    atomicAdd(&wV[(size_t)d * 128 + lane * 2 + 1], vv.y * se);
    if ((lane & 7) == 0)
        atomicAdd(&z[(size_t)d * 8 + (lane >> 3)], se);
}

// =====================================================================
extern "C" void kernel_launch(void* const* d_in, const int* in_sizes, int n_in,
                              void* d_out, int out_size, void* d_ws, size_t ws_size,
                              hipStream_t stream)
{
    const float* h    = (const float*)d_in[0];
    const int*   src  = (const int*)  d_in[1];
    const int*   dst  = (const int*)  d_in[2];
    const float* Wq   = (const float*)d_in[3];
    const float* Wk   = (const float*)d_in[4];
    const float* Wv   = (const float*)d_in[5];
    const float* Wo   = (const float*)d_in[6];
    const float* bo   = (const float*)d_in[7];
    const float* ln1g = (const float*)d_in[8];
    const float* ln1b = (const float*)d_in[9];
    const float* W1   = (const float*)d_in[10];
    const float* b1   = (const float*)d_in[11];
    const float* W2   = (const float*)d_in[12];
    const float* b2   = (const float*)d_in[13];
    const float* ln2g = (const float*)d_in[14];
    const float* ln2b = (const float*)d_in[15];

    const int N = in_sizes[0] / 128;
    const int E = in_sizes[1];

    float* ws  = (float*)d_ws;
    float* Qb  = ws;                          // N*128   (later: T, spans Qb..Kb)
    float* Kb  = ws + (size_t)N * 128;        // N*128
    float* Vb  = ws + (size_t)N * 256;        // N*128   (later: X)
    float* wV  = ws + (size_t)N * 384;        // N*128
    float* zb  = ws + (size_t)N * 512;        // N*8
    float* Xb  = Vb;
    float* Tb  = Qb;                          // N*256, overwrites dead Q,K

    const dim3 blk(256);
    const int  nb = (N + 31) / 32;            // 3125

    // 1) Q,K,V projections
    gemm128<128,false,false,false,false,false><<<dim3(nb,1), blk, 0, stream>>>(
        h, nullptr, Wq, 128, nullptr, nullptr, nullptr, nullptr, Qb, 128);
    gemm128<128,false,false,false,false,false><<<dim3(nb,1), blk, 0, stream>>>(
        h, nullptr, Wk, 128, nullptr, nullptr, nullptr, nullptr, Kb, 128);
    gemm128<128,false,false,false,false,false><<<dim3(nb,1), blk, 0, stream>>>(
        h, nullptr, Wv, 128, nullptr, nullptr, nullptr, nullptr, Vb, 128);

    // 2) edge scatter (zero accumulators first)
    hipMemsetAsync(wV, 0, (size_t)N * 128 * sizeof(float), stream);
    hipMemsetAsync(zb, 0, (size_t)N * 8   * sizeof(float), stream);
    edge_kernel<<<dim3((E + 3) / 4), blk, 0, stream>>>(Qb, Kb, Vb, src, dst, wV, zb, E);

    // 3) X = LN1(h + h_attn @ Wo + bo)
    gemm128<128,true,false,true,true,true><<<dim3(nb,1), blk, 0, stream>>>(
        wV, zb, Wo, 128, bo, h, ln1g, ln1b, Xb, 128);

    // 4) T = relu(X @ W1 + b1)   (256 cols -> 2 col tiles)
    gemm128<128,false,true,false,false,true><<<dim3(nb,2), blk, 0, stream>>>(
        Xb, nullptr, W1, 256, b1, nullptr, nullptr, nullptr, Tb, 256);

    // 5) out = LN2(X + T @ W2 + b2)
    gemm128<256,false,false,true,true,true><<<dim3(nb,1), blk, 0, stream>>>(
        Tb, nullptr, W2, 128, b2, Xb, ln2g, ln2b, (float*)d_out, 128);
}

// Round 2
// 986.515 us; speedup vs baseline: 2.0557x; 2.0557x over previous
//
#include <hip/hip_runtime.h>
#include <math.h>

// =====================================================================
// GraphTransformerLayer, round 2: CSR-by-dst aggregation (no float atomics)
//   N=100000 nodes, E=1600000 edges, D=128, H=8, DH=16, DFF=256
// Phases:
//   1) Q,K,V = h @ Wq/Wk/Wv                 (gemm128)
//   2) hist/scan/scatter: counting sort of edges by dst -> esrc[]
//   3) aggregate: wave per node, gather K[s],V[s], softmax-ish weights,
//      write normalized h_attn over Q (row dead after use)
//   4) X = LN1(h + h_attn @ Wo + bo)        (gemm128 fused)
//   5) T = relu(X @ W1 + b1)
//   6) out = LN2(X + T @ W2 + b2)
// =====================================================================

template<int K, bool RELU, bool LN, bool RESID, bool BIAS>
__global__ __launch_bounds__(256)
void gemm128(const float* __restrict__ A,
             const float* __restrict__ B, int ldb,
             const float* __restrict__ bias, const float* __restrict__ resid,
             const float* __restrict__ lng, const float* __restrict__ lnb,
             float* __restrict__ C, int ldc)
{
    __shared__ float as[32 * K];
    __shared__ float bs[64 * 128];
    __shared__ float mean_s[32];
    __shared__ float rs_s[32];

    const int tid  = threadIdx.x;
    const int row0 = blockIdx.x * 32;
    const int col0 = blockIdx.y * 128;

    // ---- stage A tile (32 x K)
    {
        const float4* A4  = (const float4*)(A + (size_t)row0 * K);
        float4*       as4 = (float4*)as;
        const int nf4 = 32 * K / 4;
        for (int i = tid; i < nf4; i += 256)
            as4[i] = A4[i];
    }

    const int colt = tid & 31;   // 32 col-threads, 4 cols each
    const int rowt = tid >> 5;   // 8 row-threads, 4 rows each
    float acc[4][4] = {{0.f}};

    for (int kc = 0; kc < K; kc += 64) {
        __syncthreads();
        {
            float4* bs4 = (float4*)bs;
            for (int i = tid; i < 2048; i += 256) {
                int r  = i >> 5;
                int c4 = i & 31;
                bs4[i] = *(const float4*)&B[(size_t)(kc + r) * ldb + col0 + c4 * 4];
            }
        }
        __syncthreads();
        for (int k = 0; k < 64; k += 4) {
            float4 a4[4];
            #pragma unroll
            for (int i = 0; i < 4; ++i)
                a4[i] = *(const float4*)&as[(rowt * 4 + i) * K + kc + k];
            #pragma unroll
            for (int kk = 0; kk < 4; ++kk) {
                float4 b4 = *(const float4*)&bs[(k + kk) * 128 + colt * 4];
                #pragma unroll
                for (int i = 0; i < 4; ++i) {
                    float a = ((const float*)&a4[i])[kk];
                    acc[i][0] += a * b4.x;
                    acc[i][1] += a * b4.y;
                    acc[i][2] += a * b4.z;
                    acc[i][3] += a * b4.w;
                }
            }
        }
    }

    float4 bv = make_float4(0.f, 0.f, 0.f, 0.f);
    if (BIAS) bv = *(const float4*)&bias[col0 + colt * 4];

    float4 vals[4];
    #pragma unroll
    for (int i = 0; i < 4; ++i) {
        float4 v;
        v.x = acc[i][0] + bv.x;
        v.y = acc[i][1] + bv.y;
        v.z = acc[i][2] + bv.z;
        v.w = acc[i][3] + bv.w;
        if (RESID) {
            const float4 rv = *(const float4*)&resid[(size_t)(row0 + rowt * 4 + i) * 128 + colt * 4];
            v.x += rv.x; v.y += rv.y; v.z += rv.z; v.w += rv.w;
        }
        if (RELU) {
            v.x = fmaxf(v.x, 0.f); v.y = fmaxf(v.y, 0.f);
            v.z = fmaxf(v.z, 0.f); v.w = fmaxf(v.w, 0.f);
        }
        vals[i] = v;
    }

    if (!LN) {
        #pragma unroll
        for (int i = 0; i < 4; ++i)
            *(float4*)&C[(size_t)(row0 + rowt * 4 + i) * ldc + col0 + colt * 4] = vals[i];
        return;
    }

    // ---- fused LayerNorm over 128-col rows (gridDim.y == 1 only)
    float* cs = bs;
    __syncthreads();
    #pragma unroll
    for (int i = 0; i < 4; ++i)
        *(float4*)&cs[(rowt * 4 + i) * 132 + colt * 4] = vals[i];
    __syncthreads();

    {
        const int r   = tid >> 3;
        const int seg = tid & 7;
        const float4* rp = (const float4*)&cs[r * 132 + seg * 16];
        float s = 0.f, sq = 0.f;
        #pragma unroll
        for (int q = 0; q < 4; ++q) {
            float4 v = rp[q];
            s  += v.x + v.y + v.z + v.w;
            sq += v.x * v.x + v.y * v.y + v.z * v.z + v.w * v.w;
        }
        s  += __shfl_xor(s, 1);  s  += __shfl_xor(s, 2);  s  += __shfl_xor(s, 4);
        sq += __shfl_xor(sq, 1); sq += __shfl_xor(sq, 2); sq += __shfl_xor(sq, 4);
        if (seg == 0) {
            float m = s * (1.f / 128.f);
            mean_s[r] = m;
            rs_s[r]   = rsqrtf(sq * (1.f / 128.f) - m * m + 1e-5f);
        }
    }
    __syncthreads();

    const float4 g4 = *(const float4*)&lng[colt * 4];
    const float4 o4 = *(const float4*)&lnb[colt * 4];
    #pragma unroll
    for (int i = 0; i < 4; ++i) {
        const int r = rowt * 4 + i;
        const float m  = mean_s[r];
        const float rs = rs_s[r];
        float4 v = vals[i];
        v.x = (v.x - m) * rs * g4.x + o4.x;
        v.y = (v.y - m) * rs * g4.y + o4.y;
        v.z = (v.z - m) * rs * g4.z + o4.z;
        v.w = (v.w - m) * rs * g4.w + o4.w;
        *(float4*)&C[(size_t)(row0 + r) * ldc + colt * 4] = v;
    }
}

// ---------------- counting sort of edges by dst ----------------
__global__ __launch_bounds__(256)
void hist_kernel(const int* __restrict__ dst, int* __restrict__ cnt, int E)
{
    int e = blockIdx.x * 256 + threadIdx.x;
    if (e < E) atomicAdd(&cnt[dst[e]], 1);
}

// exclusive scan, 2048 elements per block (256 thr x 8)
__global__ __launch_bounds__(256)
void scanA_kernel(const int* __restrict__ cnt, int* __restrict__ rowStart,
                  int* __restrict__ blockSums, int N)
{
    __shared__ int ts[256];
    const int t    = threadIdx.x;
    const int base = blockIdx.x * 2048 + t * 8;
    int v[8]; int s = 0;
    #pragma unroll
    for (int j = 0; j < 8; ++j) { v[j] = (base + j < N) ? cnt[base + j] : 0; s += v[j]; }
    ts[t] = s;
    __syncthreads();
    for (int off = 1; off < 256; off <<= 1) {
        int x = (t >= off) ? ts[t - off] : 0;
        __syncthreads();
        ts[t] += x;
        __syncthreads();
    }
    if (t == 255) blockSums[blockIdx.x] = ts[255];
    int run = ts[t] - s;   // exclusive prefix of this thread
    #pragma unroll
    for (int j = 0; j < 8; ++j) {
        if (base + j < N) rowStart[base + j] = run;
        run += v[j];
    }
}

__global__ void scanB_kernel(int* blockSums, int nb)
{
    if (threadIdx.x == 0 && blockIdx.x == 0) {
        int run = 0;
        for (int i = 0; i < nb; ++i) { int v = blockSums[i]; blockSums[i] = run; run += v; }
    }
}

__global__ __launch_bounds__(256)
void scanC_kernel(int* __restrict__ rowStart, const int* __restrict__ blockSums,
                  int N, int E)
{
    int i = blockIdx.x * 256 + threadIdx.x;
    if (i < N) rowStart[i] += blockSums[i >> 11];
    if (i == 0) rowStart[N] = E;
}

__global__ __launch_bounds__(256)
void scatter_kernel(const int* __restrict__ src, const int* __restrict__ dst,
                    const int* __restrict__ rowStart, int* __restrict__ cursor,
                    int* __restrict__ esrc, int E)
{
    int e = blockIdx.x * 256 + threadIdx.x;
    if (e >= E) return;
    int d = dst[e];
    int pos = rowStart[d] + atomicAdd(&cursor[d], 1);
    esrc[pos] = src[e];
}

// ---------------- aggregation: one wave per dst node ----------------
// Writes normalized h_attn over Q's row (Q[d] is only read by node d's wave).
__global__ __launch_bounds__(256)
void aggregate_kernel(float* __restrict__ Q, const float* __restrict__ Km,
                      const float* __restrict__ V,
                      const int* __restrict__ esrc,
                      const int* __restrict__ rowStart, int N)
{
    const int lane = threadIdx.x & 63;
    const int wid  = threadIdx.x >> 6;
    const int d    = blockIdx.x * 4 + wid;
    if (d >= N) return;

    const int beg = rowStart[d];
    const int end = rowStart[d + 1];

    const float2 qv = *(const float2*)&Q[(size_t)d * 128 + lane * 2];
    float ax = 0.f, ay = 0.f, zacc = 0.f;

    for (int base = beg; base < end; base += 64) {
        const int lim = end - base;
        int mysrc = (lane < lim) ? esrc[base + lane] : 0;
        const int n = lim < 64 ? lim : 64;
        for (int j = 0; j < n; ++j) {
            const int s = __shfl(mysrc, j);
            const float2 kv = *(const float2*)&Km[(size_t)s * 128 + lane * 2];
            const float2 vv = *(const float2*)&V [(size_t)s * 128 + lane * 2];
            float p = kv.x * qv.x + kv.y * qv.y;
            p += __shfl_xor(p, 1);
            p += __shfl_xor(p, 2);
            p += __shfl_xor(p, 4);
            float sc = fminf(5.f, fmaxf(-5.f, p * 0.25f));
            const float se = expf(sc);
            ax += vv.x * se;
            ay += vv.y * se;
            zacc += se;   // identical across the 8 lanes of a head group
        }
    }

    const float inv = 1.0f / (zacc + 1e-6f);
    *(float2*)&Q[(size_t)d * 128 + lane * 2] = make_float2(ax * inv, ay * inv);
}

// =====================================================================
extern "C" void kernel_launch(void* const* d_in, const int* in_sizes, int n_in,
                              void* d_out, int out_size, void* d_ws, size_t ws_size,
                              hipStream_t stream)
{
    const float* h    = (const float*)d_in[0];
    const int*   src  = (const int*)  d_in[1];
    const int*   dst  = (const int*)  d_in[2];
    const float* Wq   = (const float*)d_in[3];
    const float* Wk   = (const float*)d_in[4];
    const float* Wv   = (const float*)d_in[5];
    const float* Wo   = (const float*)d_in[6];
    const float* bo   = (const float*)d_in[7];
    const float* ln1g = (const float*)d_in[8];
    const float* ln1b = (const float*)d_in[9];
    const float* W1   = (const float*)d_in[10];
    const float* b1   = (const float*)d_in[11];
    const float* W2   = (const float*)d_in[12];
    const float* b2   = (const float*)d_in[13];
    const float* ln2g = (const float*)d_in[14];
    const float* ln2b = (const float*)d_in[15];

    const int N = in_sizes[0] / 128;
    const int E = in_sizes[1];

    float* ws = (float*)d_ws;
    float* Qb = ws;                          // N*128; becomes h_attn; later Tb low half
    float* Kb = ws + (size_t)N * 128;        // N*128; later Tb high half
    float* Vb = ws + (size_t)N * 256;        // N*128; later Xb
    int*   ib = (int*)(ws + (size_t)N * 384);
    int*   cnt      = ib;                    // N
    int*   rowStart = ib + N;                // N+1
    int*   cursor   = ib + 2 * N + 1;        // N
    int*   blockSums= ib + 3 * N + 1;        // <=64
    int*   esrc     = ib + 3 * N + 65;       // E
    float* Xb = Vb;
    float* Tb = Qb;                          // N*256 spans Qb+Kb (dead by then)

    const dim3 blk(256);
    const int  nb  = (N + 31) / 32;          // node row tiles
    const int  ebk = (E + 255) / 256;
    const int  nsc = (N + 2047) / 2048;      // scan blocks

    // 1) Q,K,V projections
    gemm128<128,false,false,false,false><<<dim3(nb,1), blk, 0, stream>>>(
        h, Wq, 128, nullptr, nullptr, nullptr, nullptr, Qb, 128);
    gemm128<128,false,false,false,false><<<dim3(nb,1), blk, 0, stream>>>(
        h, Wk, 128, nullptr, nullptr, nullptr, nullptr, Kb, 128);
    gemm128<128,false,false,false,false><<<dim3(nb,1), blk, 0, stream>>>(
        h, Wv, 128, nullptr, nullptr, nullptr, nullptr, Vb, 128);

    // 2) counting sort of edges by dst
    hipMemsetAsync(cnt,    0, (size_t)N * sizeof(int), stream);
    hipMemsetAsync(cursor, 0, (size_t)N * sizeof(int), stream);
    hist_kernel<<<dim3(ebk), blk, 0, stream>>>(dst, cnt, E);
    scanA_kernel<<<dim3(nsc), blk, 0, stream>>>(cnt, rowStart, blockSums, N);
    scanB_kernel<<<dim3(1), blk, 0, stream>>>(blockSums, nsc);
    scanC_kernel<<<dim3((N + 255) / 256), blk, 0, stream>>>(rowStart, blockSums, N, E);
    scatter_kernel<<<dim3(ebk), blk, 0, stream>>>(src, dst, rowStart, cursor, esrc, E);

    // 3) aggregate (h_attn written into Qb)
    aggregate_kernel<<<dim3((N + 3) / 4), blk, 0, stream>>>(Qb, Kb, Vb, esrc, rowStart, N);

    // 4) X = LN1(h + h_attn @ Wo + bo)
    gemm128<128,false,true,true,true><<<dim3(nb,1), blk, 0, stream>>>(
        Qb, Wo, 128, bo, h, ln1g, ln1b, Xb, 128);

    // 5) T = relu(X @ W1 + b1)
    gemm128<128,true,false,false,true><<<dim3(nb,2), blk, 0, stream>>>(
        Xb, W1, 256, b1, nullptr, nullptr, nullptr, Tb, 256);

    // 6) out = LN2(X + T @ W2 + b2)
    gemm128<256,false,true,true,true><<<dim3(nb,1), blk, 0, stream>>>(
        Tb, W2, 128, b2, Xb, ln2g, ln2b, (float*)d_out, 128);
}

// Round 3
// 545.949 us; speedup vs baseline: 3.7145x; 1.8070x over previous
//
#include <hip/hip_runtime.h>
#include <hip/hip_bf16.h>
#include <math.h>

// =====================================================================
// GraphTransformerLayer, round 3: bf16 MFMA GEMMs + bf16 CSR aggregation
//   N=100000, E=1600000, D=128, H=8, DH=16, DFF=256
//   1) cast h -> bf16; cast+transpose weights -> bf16
//   2) fused QKV via MFMA gemm (grid.y selects Wq/Wk/Wv)
//   3) counting sort of edges by dst
//   4) aggregate: wave/node, bf16 gathers, writes normalized h_attn (bf16)
//   5) X = LN1(h + h_attn@Wo + bo)   -> Xf (fp32) + Xh (bf16)
//   6) T = relu(X@W1 + b1)           -> bf16
//   7) out = LN2(Xf + T@W2 + b2)     -> fp32
// =====================================================================

typedef __attribute__((ext_vector_type(8))) short bf16x8;
typedef __attribute__((ext_vector_type(4))) float f32x4;

// ---------------- MFMA GEMM ----------------
// Block: 256 thr = 4 waves; tile 64 rows x 128 cols. Wave w: rows [w*16,w*16+16).
// A row-major bf16 [M x K], Bt transposed bf16 [Ncols x K] (contiguous K).
// LN/RESID assume 128 total cols (gridDim.y==1, col0==0).
// YW: blockIdx.y selects weight (QKV fusion) instead of col tile.
template<int K, bool RELU, bool LN, bool RESID, bool BIAS, bool YW>
__global__ __launch_bounds__(256)
void gemm_mfma(const __hip_bfloat16* __restrict__ A, int lda,
               const __hip_bfloat16* __restrict__ Bt, int ldbt,
               const float* __restrict__ bias, const float* __restrict__ resid,
               const float* __restrict__ lng, const float* __restrict__ lnb,
               float* __restrict__ Cf, __hip_bfloat16* __restrict__ Cb, int ldc,
               size_t bt_ystride, size_t cb_ystride, int N)
{
    constexpr int CK = 128;                       // k-chunk
    __shared__ unsigned short As[64 * 136];       // +8 pad: 2-way banks (free)
    __shared__ unsigned short Bs[128 * 136];

    const int tid  = threadIdx.x;
    const int row0 = blockIdx.x * 64;
    int col0 = 0;
    if (YW) { Bt += blockIdx.y * bt_ystride; Cb += blockIdx.y * cb_ystride; }
    else    col0 = blockIdx.y * 128;

    const int wave = tid >> 6, lane = tid & 63;
    const int quad = lane >> 4, l15 = lane & 15;

    f32x4 acc[8];
    #pragma unroll
    for (int t = 0; t < 8; ++t) acc[t] = (f32x4)0.f;

    for (int kc = 0; kc < K; kc += CK) {
        #pragma unroll
        for (int it = 0; it < 4; ++it) {          // A: 64 x 128 bf16
            int i = tid + it * 256;
            int r = i >> 4, kb = i & 15;
            int rg = row0 + r; if (rg > N - 1) rg = N - 1;
            *(uint4*)&As[r * 136 + kb * 8] =
                *(const uint4*)&A[(size_t)rg * lda + kc + kb * 8];
        }
        #pragma unroll
        for (int it = 0; it < 8; ++it) {          // Bt: 128 x 128 bf16
            int i = tid + it * 256;
            int r = i >> 4, kb = i & 15;
            *(uint4*)&Bs[r * 136 + kb * 8] =
                *(const uint4*)&Bt[(size_t)(col0 + r) * ldbt + kc + kb * 8];
        }
        __syncthreads();
        const unsigned short* ap = &As[(wave * 16 + l15) * 136 + quad * 8];
        const unsigned short* bp = &Bs[l15 * 136 + quad * 8];
        #pragma unroll
        for (int ks = 0; ks < 4; ++ks) {
            bf16x8 a = *(const bf16x8*)(ap + ks * 32);
            #pragma unroll
            for (int t = 0; t < 8; ++t) {
                bf16x8 b = *(const bf16x8*)(bp + t * 16 * 136 + ks * 32);
                acc[t] = __builtin_amdgcn_mfma_f32_16x16x32_bf16(a, b, acc[t], 0, 0, 0);
            }
        }
        __syncthreads();
    }

    // ---- epilogue: C/D layout col=l15 (per n-tile), row=quad*4+reg ----
    const int rbase = row0 + wave * 16 + quad * 4;

    float vals[8][4];
    #pragma unroll
    for (int t = 0; t < 8; ++t) {
        float bv = BIAS ? bias[col0 + t * 16 + l15] : 0.f;
        #pragma unroll
        for (int i = 0; i < 4; ++i) vals[t][i] = acc[t][i] + bv;
    }
    if (RESID) {
        #pragma unroll
        for (int i = 0; i < 4; ++i) {
            int row = rbase + i;
            if (row < N) {
                #pragma unroll
                for (int t = 0; t < 8; ++t)
                    vals[t][i] += resid[(size_t)row * 128 + t * 16 + l15];
            }
        }
    }
    if (RELU) {
        #pragma unroll
        for (int t = 0; t < 8; ++t)
            #pragma unroll
            for (int i = 0; i < 4; ++i) vals[t][i] = fmaxf(vals[t][i], 0.f);
    }
    if (LN) {
        #pragma unroll
        for (int i = 0; i < 4; ++i) {
            float s = 0.f, sq = 0.f;
            #pragma unroll
            for (int t = 0; t < 8; ++t) { float v = vals[t][i]; s += v; sq += v * v; }
            s  += __shfl_xor(s, 1);  s  += __shfl_xor(s, 2);
            s  += __shfl_xor(s, 4);  s  += __shfl_xor(s, 8);
            sq += __shfl_xor(sq, 1); sq += __shfl_xor(sq, 2);
            sq += __shfl_xor(sq, 4); sq += __shfl_xor(sq, 8);
            float m  = s * (1.f / 128.f);
            float rs = rsqrtf(sq * (1.f / 128.f) - m * m + 1e-5f);
            #pragma unroll
            for (int t = 0; t < 8; ++t) {
                float g = lng[t * 16 + l15], b = lnb[t * 16 + l15];
                vals[t][i] = (vals[t][i] - m) * rs * g + b;
            }
        }
    }
    #pragma unroll
    for (int i = 0; i < 4; ++i) {
        int row = rbase + i;
        if (row >= N) continue;
        if (Cf) {
            #pragma unroll
            for (int t = 0; t < 8; ++t)
                Cf[(size_t)row * ldc + col0 + t * 16 + l15] = vals[t][i];
        }
        if (Cb) {
            #pragma unroll
            for (int t = 0; t < 8; ++t)
                Cb[(size_t)row * ldc + col0 + t * 16 + l15] = __float2bfloat16(vals[t][i]);
        }
    }
}

// ---------------- casts ----------------
__global__ __launch_bounds__(256)
void cast_h(const float* __restrict__ h, __hip_bfloat16* __restrict__ o, int n4)
{
    int i = blockIdx.x * 256 + threadIdx.x;
    if (i >= n4) return;
    float4 a = ((const float4*)h)[i];
    *(__hip_bfloat162*)&o[i * 4]     = __float22bfloat162_rn(make_float2(a.x, a.y));
    *(__hip_bfloat162*)&o[i * 4 + 2] = __float22bfloat162_rn(make_float2(a.z, a.w));
}

struct WArgs {
    const float* src[6];
    __hip_bfloat16* dst[6];
    int R[6], C[6];
};
__global__ __launch_bounds__(256)
void cast_w(WArgs wa)
{
    int w = blockIdx.y;
    int R = wa.R[w], C = wa.C[w];
    int i = blockIdx.x * 256 + threadIdx.x;
    if (i >= R * C) return;
    int sh = (C == 256) ? 8 : 7;
    int r = i >> sh, c = i & (C - 1);
    wa.dst[w][(size_t)c * R + r] = __float2bfloat16(wa.src[w][i]);  // transpose
}

// ---------------- counting sort of edges by dst ----------------
__global__ __launch_bounds__(256)
void hist_kernel(const int* __restrict__ dst, int* __restrict__ cnt, int E)
{
    int e = blockIdx.x * 256 + threadIdx.x;
    if (e < E) atomicAdd(&cnt[dst[e]], 1);
}

__global__ __launch_bounds__(256)
void scanA_kernel(const int* __restrict__ cnt, int* __restrict__ rowStart,
                  int* __restrict__ blockSums, int N)
{
    __shared__ int ts[256];
    const int t    = threadIdx.x;
    const int base = blockIdx.x * 2048 + t * 8;
    int v[8]; int s = 0;
    #pragma unroll
    for (int j = 0; j < 8; ++j) { v[j] = (base + j < N) ? cnt[base + j] : 0; s += v[j]; }
    ts[t] = s;
    __syncthreads();
    for (int off = 1; off < 256; off <<= 1) {
        int x = (t >= off) ? ts[t - off] : 0;
        __syncthreads();
        ts[t] += x;
        __syncthreads();
    }
    if (t == 255) blockSums[blockIdx.x] = ts[255];
    int run = ts[t] - s;
    #pragma unroll
    for (int j = 0; j < 8; ++j) {
        if (base + j < N) rowStart[base + j] = run;
        run += v[j];
    }
}

__global__ void scanB_kernel(int* blockSums, int nb)
{
    if (threadIdx.x == 0 && blockIdx.x == 0) {
        int run = 0;
        for (int i = 0; i < nb; ++i) { int v = blockSums[i]; blockSums[i] = run; run += v; }
    }
}

__global__ __launch_bounds__(256)
void scanC_kernel(int* __restrict__ rowStart, const int* __restrict__ blockSums,
                  int N, int E)
{
    int i = blockIdx.x * 256 + threadIdx.x;
    if (i < N) rowStart[i] += blockSums[i >> 11];
    if (i == 0) rowStart[N] = E;
}

__global__ __launch_bounds__(256)
void scatter_kernel(const int* __restrict__ src, const int* __restrict__ dst,
                    const int* __restrict__ rowStart, int* __restrict__ cursor,
                    int* __restrict__ esrc, int E)
{
    int e = blockIdx.x * 256 + threadIdx.x;
    if (e >= E) return;
    int d = dst[e];
    int pos = rowStart[d] + atomicAdd(&cursor[d], 1);
    esrc[pos] = src[e];
}

// ---------------- aggregation: one wave per dst node (bf16 gathers) ----------------
__global__ __launch_bounds__(256)
void aggregate_kernel(__hip_bfloat16* __restrict__ Q,
                      const __hip_bfloat16* __restrict__ Km,
                      const __hip_bfloat16* __restrict__ V,
                      const int* __restrict__ esrc,
                      const int* __restrict__ rowStart, int N)
{
    const int lane = threadIdx.x & 63;
    const int wid  = threadIdx.x >> 6;
    const int d    = blockIdx.x * 4 + wid;
    if (d >= N) return;

    const int beg = rowStart[d];
    const int end = rowStart[d + 1];

    const float2 qv = __bfloat1622float2(*(const __hip_bfloat162*)&Q[(size_t)d * 128 + lane * 2]);
    float ax = 0.f, ay = 0.f, zacc = 0.f;

    for (int base = beg; base < end; base += 64) {
        const int lim = end - base;
        int mysrc = (lane < lim) ? esrc[base + lane] : 0;
        const int n = lim < 64 ? lim : 64;
        for (int j = 0; j < n; ++j) {
            const int s = __shfl(mysrc, j);
            const float2 kf = __bfloat1622float2(*(const __hip_bfloat162*)&Km[(size_t)s * 128 + lane * 2]);
            const float2 vf = __bfloat1622float2(*(const __hip_bfloat162*)&V [(size_t)s * 128 + lane * 2]);
            float p = kf.x * qv.x + kf.y * qv.y;
            p += __shfl_xor(p, 1);
            p += __shfl_xor(p, 2);
            p += __shfl_xor(p, 4);
            float sc = fminf(5.f, fmaxf(-5.f, p * 0.25f));
            const float se = __expf(sc);
            ax += vf.x * se;
            ay += vf.y * se;
            zacc += se;
        }
    }

    const float inv = 1.0f / (zacc + 1e-6f);
    *(__hip_bfloat162*)&Q[(size_t)d * 128 + lane * 2] =
        __float22bfloat162_rn(make_float2(ax * inv, ay * inv));
}

// =====================================================================
extern "C" void kernel_launch(void* const* d_in, const int* in_sizes, int n_in,
                              void* d_out, int out_size, void* d_ws, size_t ws_size,
                              hipStream_t stream)
{
    const float* h    = (const float*)d_in[0];
    const int*   src  = (const int*)  d_in[1];
    const int*   dst  = (const int*)  d_in[2];
    const float* Wq   = (const float*)d_in[3];
    const float* Wk   = (const float*)d_in[4];
    const float* Wv   = (const float*)d_in[5];
    const float* Wo   = (const float*)d_in[6];
    const float* bo   = (const float*)d_in[7];
    const float* ln1g = (const float*)d_in[8];
    const float* ln1b = (const float*)d_in[9];
    const float* W1   = (const float*)d_in[10];
    const float* b1   = (const float*)d_in[11];
    const float* W2   = (const float*)d_in[12];
    const float* b2   = (const float*)d_in[13];
    const float* ln2g = (const float*)d_in[14];
    const float* ln2b = (const float*)d_in[15];

    const int N = in_sizes[0] / 128;
    const int E = in_sizes[1];

    // ---- workspace layout (16B-aligned regions) ----
    __hip_bfloat16* hh = (__hip_bfloat16*)d_ws;        // N*128
    __hip_bfloat16* Qh = hh + (size_t)N * 128;         // N*128 (h_attn after agg)
    __hip_bfloat16* Kh = Qh + (size_t)N * 128;
    __hip_bfloat16* Vh = Kh + (size_t)N * 128;
    __hip_bfloat16* Xh = Vh + (size_t)N * 128;
    float*          Xf = (float*)(Xh + (size_t)N * 128);          // N*128 fp32
    __hip_bfloat16* Wt = (__hip_bfloat16*)(Xf + (size_t)N * 128); // 131072 bf16
    __hip_bfloat16* Wqt = Wt;                 // 128x128 (t)
    __hip_bfloat16* Wkt = Wqt + 16384;
    __hip_bfloat16* Wvt = Wkt + 16384;
    __hip_bfloat16* Wot = Wvt + 16384;
    __hip_bfloat16* W1t = Wot + 16384;        // [256][128]
    __hip_bfloat16* W2t = W1t + 32768;        // [128][256]
    int* ib       = (int*)(W2t + 32768);
    int* cnt      = ib;                       // N
    int* rowStart = ib + N;                   // N+1
    int* cursor   = ib + 2 * N + 1;           // N
    int* blockSums= ib + 3 * N + 1;           // <=64
    int* esrc     = ib + 3 * N + 65;          // E
    __hip_bfloat16* Th = hh;                  // N*256 bf16 (overlays dead hh+Qh)

    const dim3 blk(256);
    const int  nb  = (N + 63) / 64;           // 1563
    const int  ebk = (E + 255) / 256;
    const int  nsc = (N + 2047) / 2048;

    // ---- casts ----
    cast_h<<<dim3((N * 32 + 255) / 256), blk, 0, stream>>>(h, hh, N * 32);
    WArgs wa;
    wa.src[0] = Wq; wa.src[1] = Wk; wa.src[2] = Wv; wa.src[3] = Wo; wa.src[4] = W1; wa.src[5] = W2;
    wa.dst[0] = Wqt; wa.dst[1] = Wkt; wa.dst[2] = Wvt; wa.dst[3] = Wot; wa.dst[4] = W1t; wa.dst[5] = W2t;
    wa.R[0] = wa.R[1] = wa.R[2] = wa.R[3] = 128; wa.R[4] = 128; wa.R[5] = 256;
    wa.C[0] = wa.C[1] = wa.C[2] = wa.C[3] = 128; wa.C[4] = 256; wa.C[5] = 128;
    cast_w<<<dim3(128, 6), blk, 0, stream>>>(wa);

    // ---- QKV (fused: grid.y picks weight+output) ----
    gemm_mfma<128,false,false,false,false,true><<<dim3(nb, 3), blk, 0, stream>>>(
        hh, 128, Wqt, 128, nullptr, nullptr, nullptr, nullptr,
        nullptr, Qh, 128, (size_t)16384, (size_t)N * 128, N);

    // ---- counting sort of edges by dst ----
    hipMemsetAsync(cnt,    0, (size_t)N * sizeof(int), stream);
    hipMemsetAsync(cursor, 0, (size_t)N * sizeof(int), stream);
    hist_kernel<<<dim3(ebk), blk, 0, stream>>>(dst, cnt, E);
    scanA_kernel<<<dim3(nsc), blk, 0, stream>>>(cnt, rowStart, blockSums, N);
    scanB_kernel<<<dim3(1), blk, 0, stream>>>(blockSums, nsc);
    scanC_kernel<<<dim3((N + 255) / 256), blk, 0, stream>>>(rowStart, blockSums, N, E);
    scatter_kernel<<<dim3(ebk), blk, 0, stream>>>(src, dst, rowStart, cursor, esrc, E);

    // ---- aggregate (writes h_attn bf16 into Qh) ----
    aggregate_kernel<<<dim3((N + 3) / 4), blk, 0, stream>>>(Qh, Kh, Vh, esrc, rowStart, N);

    // ---- X = LN1(h + h_attn@Wo + bo): write fp32 Xf + bf16 Xh ----
    gemm_mfma<128,false,true,true,true,false><<<dim3(nb, 1), blk, 0, stream>>>(
        Qh, 128, Wot, 128, bo, h, ln1g, ln1b, Xf, Xh, 128, 0, 0, N);

    // ---- T = relu(X@W1 + b1) -> bf16 ----
    gemm_mfma<128,true,false,false,true,false><<<dim3(nb, 2), blk, 0, stream>>>(
        Xh, 128, W1t, 128, b1, nullptr, nullptr, nullptr, nullptr, Th, 256, 0, 0, N);

    // ---- out = LN2(Xf + T@W2 + b2) -> fp32 ----
    gemm_mfma<256,false,true,true,true,false><<<dim3(nb, 1), blk, 0, stream>>>(
        Th, 256, W2t, 256, b2, Xf, ln2g, ln2b, (float*)d_out, nullptr, 128, 0, 0, N);
}

// Round 4
// 537.603 us; speedup vs baseline: 3.7722x; 1.0155x over previous
//
#include <hip/hip_runtime.h>
#include <hip/hip_bf16.h>
#include <math.h>

// =====================================================================
// GraphTransformerLayer, round 4
//   - aggregate: 2 edges/wave (32 lanes each), dwordx2 bf16 gathers,
//     32-bit offsets, fused exp2 clamp, cross-half combine
//   - QKV gemm stages A straight from fp32 h (cast_h eliminated)
//   - scanC pre-inits cursor; scatter = 1 atomic only
// =====================================================================

typedef __attribute__((ext_vector_type(8))) short bf16x8;
typedef __attribute__((ext_vector_type(4))) float f32x4;

// ---------------- MFMA GEMM ----------------
// Block: 256 thr = 4 waves; tile 64 rows x 128 cols.
// A row-major (bf16, or fp32 if AF32) [M x K]; Bt transposed bf16 [Ncols x K].
// LN/RESID assume 128 total cols (gridDim.y==1). YW: blockIdx.y selects weight.
template<int K, bool AF32, bool RELU, bool LN, bool RESID, bool BIAS, bool YW>
__global__ __launch_bounds__(256)
void gemm_mfma(const void* __restrict__ Ap, int lda,
               const __hip_bfloat16* __restrict__ Bt, int ldbt,
               const float* __restrict__ bias, const float* __restrict__ resid,
               const float* __restrict__ lng, const float* __restrict__ lnb,
               float* __restrict__ Cf, __hip_bfloat16* __restrict__ Cb, int ldc,
               size_t bt_ystride, size_t cb_ystride, int N)
{
    constexpr int CK = 128;
    __shared__ unsigned short As[64 * 136];   // +8 pad (2-way bank alias: free)
    __shared__ unsigned short Bs[128 * 136];

    const int tid  = threadIdx.x;
    const int row0 = blockIdx.x * 64;
    int col0 = 0;
    if (YW) { Bt += blockIdx.y * bt_ystride; Cb += blockIdx.y * cb_ystride; }
    else    col0 = blockIdx.y * 128;

    const int wave = tid >> 6, lane = tid & 63;
    const int quad = lane >> 4, l15 = lane & 15;

    f32x4 acc[8];
    #pragma unroll
    for (int t = 0; t < 8; ++t) acc[t] = (f32x4)0.f;

    for (int kc = 0; kc < K; kc += CK) {
        #pragma unroll
        for (int it = 0; it < 4; ++it) {          // A: 64 x 128
            int i = tid + it * 256;
            int r = i >> 4, kb = i & 15;
            int rg = row0 + r; if (rg > N - 1) rg = N - 1;
            if (AF32) {
                const float* Af = (const float*)Ap;
                const float4 f0 = *(const float4*)&Af[(size_t)rg * lda + kc + kb * 8];
                const float4 f1 = *(const float4*)&Af[(size_t)rg * lda + kc + kb * 8 + 4];
                __hip_bfloat162 b01 = __float22bfloat162_rn(make_float2(f0.x, f0.y));
                __hip_bfloat162 b23 = __float22bfloat162_rn(make_float2(f0.z, f0.w));
                __hip_bfloat162 b45 = __float22bfloat162_rn(make_float2(f1.x, f1.y));
                __hip_bfloat162 b67 = __float22bfloat162_rn(make_float2(f1.z, f1.w));
                uint4 u;
                u.x = *(unsigned*)&b01; u.y = *(unsigned*)&b23;
                u.z = *(unsigned*)&b45; u.w = *(unsigned*)&b67;
                *(uint4*)&As[r * 136 + kb * 8] = u;
            } else {
                const __hip_bfloat16* Ab = (const __hip_bfloat16*)Ap;
                *(uint4*)&As[r * 136 + kb * 8] =
                    *(const uint4*)&Ab[(size_t)rg * lda + kc + kb * 8];
            }
        }
        #pragma unroll
        for (int it = 0; it < 8; ++it) {          // Bt: 128 x 128
            int i = tid + it * 256;
            int r = i >> 4, kb = i & 15;
            *(uint4*)&Bs[r * 136 + kb * 8] =
                *(const uint4*)&Bt[(size_t)(col0 + r) * ldbt + kc + kb * 8];
        }
        __syncthreads();
        const unsigned short* ap = &As[(wave * 16 + l15) * 136 + quad * 8];
        const unsigned short* bp = &Bs[l15 * 136 + quad * 8];
        #pragma unroll
        for (int ks = 0; ks < 4; ++ks) {
            bf16x8 a = *(const bf16x8*)(ap + ks * 32);
            #pragma unroll
            for (int t = 0; t < 8; ++t) {
                bf16x8 b = *(const bf16x8*)(bp + t * 16 * 136 + ks * 32);
                acc[t] = __builtin_amdgcn_mfma_f32_16x16x32_bf16(a, b, acc[t], 0, 0, 0);
            }
        }
        __syncthreads();
    }

    // ---- epilogue: C/D layout col=l15 (per n-tile), row=quad*4+reg ----
    const int rbase = row0 + wave * 16 + quad * 4;

    float vals[8][4];
    #pragma unroll
    for (int t = 0; t < 8; ++t) {
        float bv = BIAS ? bias[col0 + t * 16 + l15] : 0.f;
        #pragma unroll
        for (int i = 0; i < 4; ++i) vals[t][i] = acc[t][i] + bv;
    }
    if (RESID) {
        #pragma unroll
        for (int i = 0; i < 4; ++i) {
            int row = rbase + i;
            if (row < N) {
                #pragma unroll
                for (int t = 0; t < 8; ++t)
                    vals[t][i] += resid[(size_t)row * 128 + t * 16 + l15];
            }
        }
    }
    if (RELU) {
        #pragma unroll
        for (int t = 0; t < 8; ++t)
            #pragma unroll
            for (int i = 0; i < 4; ++i) vals[t][i] = fmaxf(vals[t][i], 0.f);
    }
    if (LN) {
        #pragma unroll
        for (int i = 0; i < 4; ++i) {
            float s = 0.f, sq = 0.f;
            #pragma unroll
            for (int t = 0; t < 8; ++t) { float v = vals[t][i]; s += v; sq += v * v; }
            s  += __shfl_xor(s, 1);  s  += __shfl_xor(s, 2);
            s  += __shfl_xor(s, 4);  s  += __shfl_xor(s, 8);
            sq += __shfl_xor(sq, 1); sq += __shfl_xor(sq, 2);
            sq += __shfl_xor(sq, 4); sq += __shfl_xor(sq, 8);
            float m  = s * (1.f / 128.f);
            float rs = rsqrtf(sq * (1.f / 128.f) - m * m + 1e-5f);
            #pragma unroll
            for (int t = 0; t < 8; ++t) {
                float g = lng[t * 16 + l15], b = lnb[t * 16 + l15];
                vals[t][i] = (vals[t][i] - m) * rs * g + b;
            }
        }
    }
    #pragma unroll
    for (int i = 0; i < 4; ++i) {
        int row = rbase + i;
        if (row >= N) continue;
        if (Cf) {
            #pragma unroll
            for (int t = 0; t < 8; ++t)
                Cf[(size_t)row * ldc + col0 + t * 16 + l15] = vals[t][i];
        }
        if (Cb) {
            #pragma unroll
            for (int t = 0; t < 8; ++t)
                Cb[(size_t)row * ldc + col0 + t * 16 + l15] = __float2bfloat16(vals[t][i]);
        }
    }
}

// ---------------- weight cast+transpose ----------------
struct WArgs {
    const float* src[6];
    __hip_bfloat16* dst[6];
    int R[6], C[6];
};
__global__ __launch_bounds__(256)
void cast_w(WArgs wa)
{
    int w = blockIdx.y;
    int R = wa.R[w], C = wa.C[w];
    int i = blockIdx.x * 256 + threadIdx.x;
    if (i >= R * C) return;
    int sh = (C == 256) ? 8 : 7;
    int r = i >> sh, c = i & (C - 1);
    wa.dst[w][(size_t)c * R + r] = __float2bfloat16(wa.src[w][i]);  // transpose
}

// ---------------- counting sort of edges by dst ----------------
__global__ __launch_bounds__(256)
void hist_kernel(const int* __restrict__ dst, int* __restrict__ cnt, int E)
{
    int e = blockIdx.x * 256 + threadIdx.x;
    if (e < E) atomicAdd(&cnt[dst[e]], 1);
}

__global__ __launch_bounds__(256)
void scanA_kernel(const int* __restrict__ cnt, int* __restrict__ rowStart,
                  int* __restrict__ blockSums, int N)
{
    __shared__ int ts[256];
    const int t    = threadIdx.x;
    const int base = blockIdx.x * 2048 + t * 8;
    int v[8]; int s = 0;
    #pragma unroll
    for (int j = 0; j < 8; ++j) { v[j] = (base + j < N) ? cnt[base + j] : 0; s += v[j]; }
    ts[t] = s;
    __syncthreads();
    for (int off = 1; off < 256; off <<= 1) {
        int x = (t >= off) ? ts[t - off] : 0;
        __syncthreads();
        ts[t] += x;
        __syncthreads();
    }
    if (t == 255) blockSums[blockIdx.x] = ts[255];
    int run = ts[t] - s;
    #pragma unroll
    for (int j = 0; j < 8; ++j) {
        if (base + j < N) rowStart[base + j] = run;
        run += v[j];
    }
}

__global__ void scanB_kernel(int* blockSums, int nb)
{
    if (threadIdx.x == 0 && blockIdx.x == 0) {
        int run = 0;
        for (int i = 0; i < nb; ++i) { int v = blockSums[i]; blockSums[i] = run; run += v; }
    }
}

__global__ __launch_bounds__(256)
void scanC_kernel(int* __restrict__ rowStart, int* __restrict__ cursor,
                  const int* __restrict__ blockSums, int N, int E)
{
    int i = blockIdx.x * 256 + threadIdx.x;
    if (i < N) {
        int v = rowStart[i] + blockSums[i >> 11];
        rowStart[i] = v;
        cursor[i]   = v;          // scatter uses cursor directly
    }
    if (i == 0) rowStart[N] = E;
}

__global__ __launch_bounds__(256)
void scatter_kernel(const int* __restrict__ src, const int* __restrict__ dst,
                    int* __restrict__ cursor, int* __restrict__ esrc, int E)
{
    int e = blockIdx.x * 256 + threadIdx.x;
    if (e >= E) return;
    int pos = atomicAdd(&cursor[dst[e]], 1);
    esrc[pos] = src[e];
}

// ---------------- aggregation: wave = 2 edges (32 lanes each) ----------------
// Lane l5 owns 4 contiguous elements [l5*4, l5*4+4) -> single head (l5>>2).
// Writes normalized h_attn (bf16) over Q row.
__global__ __launch_bounds__(256)
void aggregate_kernel(__hip_bfloat16* __restrict__ Q,
                      const __hip_bfloat16* __restrict__ Km,
                      const __hip_bfloat16* __restrict__ V,
                      const int* __restrict__ esrc,
                      const int* __restrict__ rowStart, int N)
{
    const int lane = threadIdx.x & 63;
    const int wid  = threadIdx.x >> 6;
    const int d    = blockIdx.x * 4 + wid;
    if (d >= N) return;

    const int l5   = lane & 31;
    const int half = lane >> 5;

    const uint2* K2 = (const uint2*)Km;
    const uint2* V2 = (const uint2*)V;
    uint2*       Q2 = (uint2*)Q;

    const uint2 qraw = Q2[(unsigned)d * 32u + (unsigned)l5];
    const float q0 = __uint_as_float(qraw.x << 16);
    const float q1 = __uint_as_float(qraw.x & 0xffff0000u);
    const float q2 = __uint_as_float(qraw.y << 16);
    const float q3 = __uint_as_float(qraw.y & 0xffff0000u);

    const int beg = rowStart[d];
    const int end = rowStart[d + 1];

    float a0 = 0.f, a1 = 0.f, a2 = 0.f, a3 = 0.f, zacc = 0.f;
    const float S = 0.36067376022224085f;  // 0.25 * log2(e)
    const float C = 7.2134752044448170f;   // 5 * log2(e)

    for (int base = beg; base < end; base += 64) {
        int n = end - base; if (n > 64) n = 64;
        int mysrc = (lane < n) ? esrc[base + lane] : 0;
        const int nf = n >> 1;
        int bidx = half;
        for (int j = 0; j < nf; ++j, bidx += 2) {
            const int s = __shfl(mysrc, bidx);
            const unsigned off = (unsigned)s * 32u + (unsigned)l5;
            const uint2 kraw = K2[off];
            const uint2 vraw = V2[off];
            float p = __uint_as_float(kraw.x << 16)        * q0
                    + __uint_as_float(kraw.x & 0xffff0000u) * q1
                    + __uint_as_float(kraw.y << 16)        * q2
                    + __uint_as_float(kraw.y & 0xffff0000u) * q3;
            p += __shfl_xor(p, 1);
            p += __shfl_xor(p, 2);
            const float t  = fminf(C, fmaxf(-C, p * S));
            const float se = exp2f(t);
            a0 += __uint_as_float(vraw.x << 16)         * se;
            a1 += __uint_as_float(vraw.x & 0xffff0000u) * se;
            a2 += __uint_as_float(vraw.y << 16)         * se;
            a3 += __uint_as_float(vraw.y & 0xffff0000u) * se;
            zacc += se;
        }
        if (n & 1) {
            const int s = __shfl(mysrc, n - 1);
            const unsigned off = (unsigned)s * 32u + (unsigned)l5;
            const uint2 kraw = K2[off];
            const uint2 vraw = V2[off];
            float p = __uint_as_float(kraw.x << 16)        * q0
                    + __uint_as_float(kraw.x & 0xffff0000u) * q1
                    + __uint_as_float(kraw.y << 16)        * q2
                    + __uint_as_float(kraw.y & 0xffff0000u) * q3;
            p += __shfl_xor(p, 1);
            p += __shfl_xor(p, 2);
            const float t  = fminf(C, fmaxf(-C, p * S));
            float se = exp2f(t);
            se = half ? 0.f : se;              // only half 0 owns the odd edge
            a0 += __uint_as_float(vraw.x << 16)         * se;
            a1 += __uint_as_float(vraw.x & 0xffff0000u) * se;
            a2 += __uint_as_float(vraw.y << 16)         * se;
            a3 += __uint_as_float(vraw.y & 0xffff0000u) * se;
            zacc += se;
        }
    }

    // combine the two halves
    a0 += __shfl_xor(a0, 32); a1 += __shfl_xor(a1, 32);
    a2 += __shfl_xor(a2, 32); a3 += __shfl_xor(a3, 32);
    zacc += __shfl_xor(zacc, 32);

    if (half == 0) {
        const float inv = 1.0f / (zacc + 1e-6f);
        __hip_bfloat162 p0 = __float22bfloat162_rn(make_float2(a0 * inv, a1 * inv));
        __hip_bfloat162 p1 = __float22bfloat162_rn(make_float2(a2 * inv, a3 * inv));
        uint2 o;
        o.x = *(unsigned*)&p0;
        o.y = *(unsigned*)&p1;
        Q2[(unsigned)d * 32u + (unsigned)l5] = o;
    }
}

// =====================================================================
extern "C" void kernel_launch(void* const* d_in, const int* in_sizes, int n_in,
                              void* d_out, int out_size, void* d_ws, size_t ws_size,
                              hipStream_t stream)
{
    const float* h    = (const float*)d_in[0];
    const int*   src  = (const int*)  d_in[1];
    const int*   dst  = (const int*)  d_in[2];
    const float* Wq   = (const float*)d_in[3];
    const float* Wk   = (const float*)d_in[4];
    const float* Wv   = (const float*)d_in[5];
    const float* Wo   = (const float*)d_in[6];
    const float* bo   = (const float*)d_in[7];
    const float* ln1g = (const float*)d_in[8];
    const float* ln1b = (const float*)d_in[9];
    const float* W1   = (const float*)d_in[10];
    const float* b1   = (const float*)d_in[11];
    const float* W2   = (const float*)d_in[12];
    const float* b2   = (const float*)d_in[13];
    const float* ln2g = (const float*)d_in[14];
    const float* ln2b = (const float*)d_in[15];

    const int N = in_sizes[0] / 128;
    const int E = in_sizes[1];

    // ---- workspace layout ----
    __hip_bfloat16* Qh = (__hip_bfloat16*)d_ws;        // N*128 (h_attn after agg)
    __hip_bfloat16* Kh = Qh + (size_t)N * 128;
    __hip_bfloat16* Vh = Kh + (size_t)N * 128;
    __hip_bfloat16* Xh = Vh + (size_t)N * 128;
    float*          Xf = (float*)(Xh + (size_t)N * 128);          // N*128 fp32
    __hip_bfloat16* Wt = (__hip_bfloat16*)(Xf + (size_t)N * 128); // 131072 bf16
    __hip_bfloat16* Wqt = Wt;                 // 128x128 (t)
    __hip_bfloat16* Wkt = Wqt + 16384;
    __hip_bfloat16* Wvt = Wkt + 16384;
    __hip_bfloat16* Wot = Wvt + 16384;
    __hip_bfloat16* W1t = Wot + 16384;        // [256][128]
    __hip_bfloat16* W2t = W1t + 32768;        // [128][256]
    int* ib       = (int*)(W2t + 32768);
    int* cnt      = ib;                       // N
    int* rowStart = ib + N;                   // N+1
    int* cursor   = ib + 2 * N + 1;           // N
    int* blockSums= ib + 3 * N + 1;           // <=64
    int* esrc     = ib + 3 * N + 65;          // E
    __hip_bfloat16* Th = Qh;                  // N*256 bf16 overlay (Qh+Kh dead)

    const dim3 blk(256);
    const int  nb  = (N + 63) / 64;
    const int  ebk = (E + 255) / 256;
    const int  nsc = (N + 2047) / 2048;

    // ---- weight cast+transpose ----
    WArgs wa;
    wa.src[0] = Wq; wa.src[1] = Wk; wa.src[2] = Wv; wa.src[3] = Wo; wa.src[4] = W1; wa.src[5] = W2;
    wa.dst[0] = Wqt; wa.dst[1] = Wkt; wa.dst[2] = Wvt; wa.dst[3] = Wot; wa.dst[4] = W1t; wa.dst[5] = W2t;
    wa.R[0] = wa.R[1] = wa.R[2] = wa.R[3] = 128; wa.R[4] = 128; wa.R[5] = 256;
    wa.C[0] = wa.C[1] = wa.C[2] = wa.C[3] = 128; wa.C[4] = 256; wa.C[5] = 128;
    cast_w<<<dim3(128, 6), blk, 0, stream>>>(wa);

    // ---- QKV (A = fp32 h, converted during LDS staging) ----
    gemm_mfma<128,true,false,false,false,false,true><<<dim3(nb, 3), blk, 0, stream>>>(
        h, 128, Wqt, 128, nullptr, nullptr, nullptr, nullptr,
        nullptr, Qh, 128, (size_t)16384, (size_t)N * 128, N);

    // ---- counting sort of edges by dst ----
    hipMemsetAsync(cnt, 0, (size_t)N * sizeof(int), stream);
    hist_kernel<<<dim3(ebk), blk, 0, stream>>>(dst, cnt, E);
    scanA_kernel<<<dim3(nsc), blk, 0, stream>>>(cnt, rowStart, blockSums, N);
    scanB_kernel<<<dim3(1), blk, 0, stream>>>(blockSums, nsc);
    scanC_kernel<<<dim3((N + 255) / 256), blk, 0, stream>>>(rowStart, cursor, blockSums, N, E);
    scatter_kernel<<<dim3(ebk), blk, 0, stream>>>(src, dst, cursor, esrc, E);

    // ---- aggregate (writes h_attn bf16 into Qh) ----
    aggregate_kernel<<<dim3((N + 3) / 4), blk, 0, stream>>>(Qh, Kh, Vh, esrc, rowStart, N);

    // ---- X = LN1(h + h_attn@Wo + bo): write fp32 Xf + bf16 Xh ----
    gemm_mfma<128,false,false,true,true,true,false><<<dim3(nb, 1), blk, 0, stream>>>(
        Qh, 128, Wot, 128, bo, h, ln1g, ln1b, Xf, Xh, 128, 0, 0, N);

    // ---- T = relu(X@W1 + b1) -> bf16 ----
    gemm_mfma<128,false,true,false,false,true,false><<<dim3(nb, 2), blk, 0, stream>>>(
        Xh, 128, W1t, 128, b1, nullptr, nullptr, nullptr, nullptr, Th, 256, 0, 0, N);

    // ---- out = LN2(Xf + T@W2 + b2) -> fp32 ----
    gemm_mfma<256,false,false,true,true,true,false><<<dim3(nb, 1), blk, 0, stream>>>(
        Th, 256, W2t, 256, b2, Xf, ln2g, ln2b, (float*)d_out, nullptr, 128, 0, 0, N);
}

// Round 5
// 423.565 us; speedup vs baseline: 4.7878x; 1.2692x over previous
//
#include <hip/hip_runtime.h>
#include <hip/hip_bf16.h>
#include <math.h>

// =====================================================================
// GraphTransformerLayer, round 5
//   - two-level bucketed counting sort (dst>>9 buckets) replaces the
//     thrashing single-level scatter: all scattered writes now land in
//     small L2-resident regions (each line written back once)
//   - aggregate: 2 edges/wave (32 lanes each), unchanged from r4
//   - MFMA GEMMs unchanged
// =====================================================================

typedef __attribute__((ext_vector_type(8))) short bf16x8;
typedef __attribute__((ext_vector_type(4))) float f32x4;

#define BSHIFT 9
#define BSIZE  512

// ---------------- MFMA GEMM ----------------
template<int K, bool AF32, bool RELU, bool LN, bool RESID, bool BIAS, bool YW>
__global__ __launch_bounds__(256)
void gemm_mfma(const void* __restrict__ Ap, int lda,
               const __hip_bfloat16* __restrict__ Bt, int ldbt,
               const float* __restrict__ bias, const float* __restrict__ resid,
               const float* __restrict__ lng, const float* __restrict__ lnb,
               float* __restrict__ Cf, __hip_bfloat16* __restrict__ Cb, int ldc,
               size_t bt_ystride, size_t cb_ystride, int N)
{
    constexpr int CK = 128;
    __shared__ unsigned short As[64 * 136];
    __shared__ unsigned short Bs[128 * 136];

    const int tid  = threadIdx.x;
    const int row0 = blockIdx.x * 64;
    int col0 = 0;
    if (YW) { Bt += blockIdx.y * bt_ystride; Cb += blockIdx.y * cb_ystride; }
    else    col0 = blockIdx.y * 128;

    const int wave = tid >> 6, lane = tid & 63;
    const int quad = lane >> 4, l15 = lane & 15;

    f32x4 acc[8];
    #pragma unroll
    for (int t = 0; t < 8; ++t) acc[t] = (f32x4)0.f;

    for (int kc = 0; kc < K; kc += CK) {
        #pragma unroll
        for (int it = 0; it < 4; ++it) {          // A: 64 x 128
            int i = tid + it * 256;
            int r = i >> 4, kb = i & 15;
            int rg = row0 + r; if (rg > N - 1) rg = N - 1;
            if (AF32) {
                const float* Af = (const float*)Ap;
                const float4 f0 = *(const float4*)&Af[(size_t)rg * lda + kc + kb * 8];
                const float4 f1 = *(const float4*)&Af[(size_t)rg * lda + kc + kb * 8 + 4];
                __hip_bfloat162 b01 = __float22bfloat162_rn(make_float2(f0.x, f0.y));
                __hip_bfloat162 b23 = __float22bfloat162_rn(make_float2(f0.z, f0.w));
                __hip_bfloat162 b45 = __float22bfloat162_rn(make_float2(f1.x, f1.y));
                __hip_bfloat162 b67 = __float22bfloat162_rn(make_float2(f1.z, f1.w));
                uint4 u;
                u.x = *(unsigned*)&b01; u.y = *(unsigned*)&b23;
                u.z = *(unsigned*)&b45; u.w = *(unsigned*)&b67;
                *(uint4*)&As[r * 136 + kb * 8] = u;
            } else {
                const __hip_bfloat16* Ab = (const __hip_bfloat16*)Ap;
                *(uint4*)&As[r * 136 + kb * 8] =
                    *(const uint4*)&Ab[(size_t)rg * lda + kc + kb * 8];
            }
        }
        #pragma unroll
        for (int it = 0; it < 8; ++it) {          // Bt: 128 x 128
            int i = tid + it * 256;
            int r = i >> 4, kb = i & 15;
            *(uint4*)&Bs[r * 136 + kb * 8] =
                *(const uint4*)&Bt[(size_t)(col0 + r) * ldbt + kc + kb * 8];
        }
        __syncthreads();
        const unsigned short* ap = &As[(wave * 16 + l15) * 136 + quad * 8];
        const unsigned short* bp = &Bs[l15 * 136 + quad * 8];
        #pragma unroll
        for (int ks = 0; ks < 4; ++ks) {
            bf16x8 a = *(const bf16x8*)(ap + ks * 32);
            #pragma unroll
            for (int t = 0; t < 8; ++t) {
                bf16x8 b = *(const bf16x8*)(bp + t * 16 * 136 + ks * 32);
                acc[t] = __builtin_amdgcn_mfma_f32_16x16x32_bf16(a, b, acc[t], 0, 0, 0);
            }
        }
        __syncthreads();
    }

    const int rbase = row0 + wave * 16 + quad * 4;

    float vals[8][4];
    #pragma unroll
    for (int t = 0; t < 8; ++t) {
        float bv = BIAS ? bias[col0 + t * 16 + l15] : 0.f;
        #pragma unroll
        for (int i = 0; i < 4; ++i) vals[t][i] = acc[t][i] + bv;
    }
    if (RESID) {
        #pragma unroll
        for (int i = 0; i < 4; ++i) {
            int row = rbase + i;
            if (row < N) {
                #pragma unroll
                for (int t = 0; t < 8; ++t)
                    vals[t][i] += resid[(size_t)row * 128 + t * 16 + l15];
            }
        }
    }
    if (RELU) {
        #pragma unroll
        for (int t = 0; t < 8; ++t)
            #pragma unroll
            for (int i = 0; i < 4; ++i) vals[t][i] = fmaxf(vals[t][i], 0.f);
    }
    if (LN) {
        #pragma unroll
        for (int i = 0; i < 4; ++i) {
            float s = 0.f, sq = 0.f;
            #pragma unroll
            for (int t = 0; t < 8; ++t) { float v = vals[t][i]; s += v; sq += v * v; }
            s  += __shfl_xor(s, 1);  s  += __shfl_xor(s, 2);
            s  += __shfl_xor(s, 4);  s  += __shfl_xor(s, 8);
            sq += __shfl_xor(sq, 1); sq += __shfl_xor(sq, 2);
            sq += __shfl_xor(sq, 4); sq += __shfl_xor(sq, 8);
            float m  = s * (1.f / 128.f);
            float rs = rsqrtf(sq * (1.f / 128.f) - m * m + 1e-5f);
            #pragma unroll
            for (int t = 0; t < 8; ++t) {
                float g = lng[t * 16 + l15], b = lnb[t * 16 + l15];
                vals[t][i] = (vals[t][i] - m) * rs * g + b;
            }
        }
    }
    #pragma unroll
    for (int i = 0; i < 4; ++i) {
        int row = rbase + i;
        if (row >= N) continue;
        if (Cf) {
            #pragma unroll
            for (int t = 0; t < 8; ++t)
                Cf[(size_t)row * ldc + col0 + t * 16 + l15] = vals[t][i];
        }
        if (Cb) {
            #pragma unroll
            for (int t = 0; t < 8; ++t)
                Cb[(size_t)row * ldc + col0 + t * 16 + l15] = __float2bfloat16(vals[t][i]);
        }
    }
}

// ---------------- weight cast+transpose ----------------
struct WArgs {
    const float* src[6];
    __hip_bfloat16* dst[6];
    int R[6], C[6];
};
__global__ __launch_bounds__(256)
void cast_w(WArgs wa)
{
    int w = blockIdx.y;
    int R = wa.R[w], C = wa.C[w];
    int i = blockIdx.x * 256 + threadIdx.x;
    if (i >= R * C) return;
    int sh = (C == 256) ? 8 : 7;
    int r = i >> sh, c = i & (C - 1);
    wa.dst[w][(size_t)c * R + r] = __float2bfloat16(wa.src[w][i]);
}

// ---------------- two-level bucketed sort of edges by dst ----------------
// Level 1: buckets of BSIZE consecutive dst values (NB = ceil(N/BSIZE) <= 256).

// Per-block LDS histogram over buckets -> global bucket counts.
__global__ __launch_bounds__(256)
void bucket_hist(const int* __restrict__ dst, int* __restrict__ bCnt,
                 int E, int chunk, int NB)
{
    __shared__ int bh[256];
    const int t = threadIdx.x;
    bh[t] = 0;
    __syncthreads();
    const int s0 = blockIdx.x * chunk;
    const int s1 = min(E, s0 + chunk);
    for (int i = s0 + t; i < s1; i += 256)
        atomicAdd(&bh[dst[i] >> BSHIFT], 1);
    __syncthreads();
    if (t < NB && bh[t]) atomicAdd(&bCnt[t], bh[t]);
}

// Scan bucket counts -> bucketBase; init global cursors; rowStart[N]=E.
__global__ __launch_bounds__(256)
void bucket_scan(const int* __restrict__ bCnt, int* __restrict__ bBase,
                 int* __restrict__ gCur, int* __restrict__ rowStart,
                 int N, int E, int NB)
{
    __shared__ int wsum[4];
    const int t = threadIdx.x, lane = t & 63, wv = t >> 6;
    int v = (t < NB) ? bCnt[t] : 0;
    const int s = v;
    for (int off = 1; off < 64; off <<= 1) {
        int u = __shfl_up(v, off);
        if (lane >= off) v += u;
    }
    if (lane == 63) wsum[wv] = v;
    __syncthreads();
    int add = 0;
    for (int w = 0; w < wv; ++w) add += wsum[w];
    const int excl = v + add - s;
    if (t <= NB) bBase[t] = excl;
    if (t < NB)  gCur[t]  = excl;
    if (t == 0)  rowStart[N] = E;
}

// Partition (src,dst) pairs into bucket regions of P.
// Each block reserves contiguous per-bucket ranges (1 fetch-add/bucket), so
// writes are ~40-entry contiguous runs: each line written once.
__global__ __launch_bounds__(256)
void partition_kernel(const int* __restrict__ src, const int* __restrict__ dst,
                      int* __restrict__ gCur, uint2* __restrict__ P,
                      int E, int chunk, int NB)
{
    __shared__ int ch[256];
    __shared__ int cur[256];
    const int t = threadIdx.x;
    ch[t] = 0;
    __syncthreads();
    const int s0 = blockIdx.x * chunk;
    const int s1 = min(E, s0 + chunk);
    for (int i = s0 + t; i < s1; i += 256)
        atomicAdd(&ch[dst[i] >> BSHIFT], 1);
    __syncthreads();
    if (t < NB) {
        int c = ch[t];
        cur[t] = c ? atomicAdd(&gCur[t], c) : 0;
    }
    __syncthreads();
    for (int i = s0 + t; i < s1; i += 256) {
        int d = dst[i];
        int pos = atomicAdd(&cur[d >> BSHIFT], 1);
        P[pos] = make_uint2((unsigned)src[i], (unsigned)d);
    }
}

// One block per bucket: LDS hist over its 512 dsts, LDS scan, write rowStart,
// scatter esrc within the bucket's contiguous (L2-resident) region.
__global__ __launch_bounds__(256)
void bucket_scatter(const uint2* __restrict__ P, const int* __restrict__ bBase,
                    int* __restrict__ rowStart, int* __restrict__ esrc, int N)
{
    __shared__ int hist[BSIZE];
    __shared__ int cur[BSIZE];
    __shared__ int wsum[4];

    const int b  = blockIdx.x;
    const int t  = threadIdx.x;
    const int d0 = b << BSHIFT;
    const int bb  = bBase[b];
    const int cnt = bBase[b + 1] - bb;

    hist[t] = 0; hist[t + 256] = 0;
    __syncthreads();
    for (int i = t; i < cnt; i += 256)
        atomicAdd(&hist[(int)P[bb + i].y - d0], 1);
    __syncthreads();

    // exclusive scan of 512 entries (2 per thread)
    {
        const int a0 = hist[2 * t], a1 = hist[2 * t + 1];
        int v = a0 + a1;
        const int s = v;
        const int lane = t & 63, wv = t >> 6;
        for (int off = 1; off < 64; off <<= 1) {
            int u = __shfl_up(v, off);
            if (lane >= off) v += u;
        }
        if (lane == 63) wsum[wv] = v;
        __syncthreads();
        int add = 0;
        for (int w = 0; w < wv; ++w) add += wsum[w];
        const int exclT = v + add - s;
        cur[2 * t]     = exclT;
        cur[2 * t + 1] = exclT + a0;
    }
    __syncthreads();
    // rowStart (coalesced) — must complete before cursors mutate
    for (int i = t; i < BSIZE; i += 256) {
        int d = d0 + i;
        if (d < N) rowStart[d] = bb + cur[i];
    }
    __syncthreads();
    for (int i = t; i < cnt; i += 256) {
        uint2 p = P[bb + i];
        int pos = atomicAdd(&cur[(int)p.y - d0], 1);
        esrc[bb + pos] = (int)p.x;
    }
}

// ---------------- aggregation: wave = 2 edges (32 lanes each) ----------------
__global__ __launch_bounds__(256)
void aggregate_kernel(__hip_bfloat16* __restrict__ Q,
                      const __hip_bfloat16* __restrict__ Km,
                      const __hip_bfloat16* __restrict__ V,
                      const int* __restrict__ esrc,
                      const int* __restrict__ rowStart, int N)
{
    const int lane = threadIdx.x & 63;
    const int wid  = threadIdx.x >> 6;
    const int d    = blockIdx.x * 4 + wid;
    if (d >= N) return;

    const int l5   = lane & 31;
    const int half = lane >> 5;

    const uint2* K2 = (const uint2*)Km;
    const uint2* V2 = (const uint2*)V;
    uint2*       Q2 = (uint2*)Q;

    const uint2 qraw = Q2[(unsigned)d * 32u + (unsigned)l5];
    const float q0 = __uint_as_float(qraw.x << 16);
    const float q1 = __uint_as_float(qraw.x & 0xffff0000u);
    const float q2 = __uint_as_float(qraw.y << 16);
    const float q3 = __uint_as_float(qraw.y & 0xffff0000u);

    const int beg = rowStart[d];
    const int end = rowStart[d + 1];

    float a0 = 0.f, a1 = 0.f, a2 = 0.f, a3 = 0.f, zacc = 0.f;
    const float S = 0.36067376022224085f;  // 0.25 * log2(e)
    const float C = 7.2134752044448170f;   // 5 * log2(e)

    for (int base = beg; base < end; base += 64) {
        int n = end - base; if (n > 64) n = 64;
        int mysrc = (lane < n) ? esrc[base + lane] : 0;
        const int nf = n >> 1;
        int bidx = half;
        for (int j = 0; j < nf; ++j, bidx += 2) {
            const int s = __shfl(mysrc, bidx);
            const unsigned off = (unsigned)s * 32u + (unsigned)l5;
            const uint2 kraw = K2[off];
            const uint2 vraw = V2[off];
            float p = __uint_as_float(kraw.x << 16)         * q0
                    + __uint_as_float(kraw.x & 0xffff0000u) * q1
                    + __uint_as_float(kraw.y << 16)         * q2
                    + __uint_as_float(kraw.y & 0xffff0000u) * q3;
            p += __shfl_xor(p, 1);
            p += __shfl_xor(p, 2);
            const float tt = fminf(C, fmaxf(-C, p * S));
            const float se = exp2f(tt);
            a0 += __uint_as_float(vraw.x << 16)         * se;
            a1 += __uint_as_float(vraw.x & 0xffff0000u) * se;
            a2 += __uint_as_float(vraw.y << 16)         * se;
            a3 += __uint_as_float(vraw.y & 0xffff0000u) * se;
            zacc += se;
        }
        if (n & 1) {
            const int s = __shfl(mysrc, n - 1);
            const unsigned off = (unsigned)s * 32u + (unsigned)l5;
            const uint2 kraw = K2[off];
            const uint2 vraw = V2[off];
            float p = __uint_as_float(kraw.x << 16)         * q0
                    + __uint_as_float(kraw.x & 0xffff0000u) * q1
                    + __uint_as_float(kraw.y << 16)         * q2
                    + __uint_as_float(kraw.y & 0xffff0000u) * q3;
            p += __shfl_xor(p, 1);
            p += __shfl_xor(p, 2);
            const float tt = fminf(C, fmaxf(-C, p * S));
            float se = exp2f(tt);
            se = half ? 0.f : se;
            a0 += __uint_as_float(vraw.x << 16)         * se;
            a1 += __uint_as_float(vraw.x & 0xffff0000u) * se;
            a2 += __uint_as_float(vraw.y << 16)         * se;
            a3 += __uint_as_float(vraw.y & 0xffff0000u) * se;
            zacc += se;
        }
    }

    a0 += __shfl_xor(a0, 32); a1 += __shfl_xor(a1, 32);
    a2 += __shfl_xor(a2, 32); a3 += __shfl_xor(a3, 32);
    zacc += __shfl_xor(zacc, 32);

    if (half == 0) {
        const float inv = 1.0f / (zacc + 1e-6f);
        __hip_bfloat162 p0 = __float22bfloat162_rn(make_float2(a0 * inv, a1 * inv));
        __hip_bfloat162 p1 = __float22bfloat162_rn(make_float2(a2 * inv, a3 * inv));
        uint2 o;
        o.x = *(unsigned*)&p0;
        o.y = *(unsigned*)&p1;
        Q2[(unsigned)d * 32u + (unsigned)l5] = o;
    }
}

// =====================================================================
extern "C" void kernel_launch(void* const* d_in, const int* in_sizes, int n_in,
                              void* d_out, int out_size, void* d_ws, size_t ws_size,
                              hipStream_t stream)
{
    const float* h    = (const float*)d_in[0];
    const int*   src  = (const int*)  d_in[1];
    const int*   dst  = (const int*)  d_in[2];
    const float* Wq   = (const float*)d_in[3];
    const float* Wk   = (const float*)d_in[4];
    const float* Wv   = (const float*)d_in[5];
    const float* Wo   = (const float*)d_in[6];
    const float* bo   = (const float*)d_in[7];
    const float* ln1g = (const float*)d_in[8];
    const float* ln1b = (const float*)d_in[9];
    const float* W1   = (const float*)d_in[10];
    const float* b1   = (const float*)d_in[11];
    const float* W2   = (const float*)d_in[12];
    const float* b2   = (const float*)d_in[13];
    const float* ln2g = (const float*)d_in[14];
    const float* ln2b = (const float*)d_in[15];

    const int N = in_sizes[0] / 128;
    const int E = in_sizes[1];
    const int NB = (N + BSIZE - 1) >> BSHIFT;   // <= 256 for N <= 131072

    // ---- workspace layout ----
    __hip_bfloat16* Qh = (__hip_bfloat16*)d_ws;        // N*128 (h_attn after agg)
    __hip_bfloat16* Kh = Qh + (size_t)N * 128;
    __hip_bfloat16* Vh = Kh + (size_t)N * 128;
    __hip_bfloat16* Xh = Vh + (size_t)N * 128;
    float*          Xf = (float*)(Xh + (size_t)N * 128);          // N*128 fp32
    __hip_bfloat16* Wt = (__hip_bfloat16*)(Xf + (size_t)N * 128);
    __hip_bfloat16* Wqt = Wt;
    __hip_bfloat16* Wkt = Wqt + 16384;
    __hip_bfloat16* Wvt = Wkt + 16384;
    __hip_bfloat16* Wot = Wvt + 16384;
    __hip_bfloat16* W1t = Wot + 16384;        // [256][128]
    __hip_bfloat16* W2t = W1t + 32768;        // [128][256]
    int* ib       = (int*)(W2t + 32768);
    int* bCnt     = ib;                       // 256
    int* bBase    = ib + 256;                 // 257
    int* gCur     = ib + 514;                 // 256
    int* rowStart = ib + 770;                 // N+1
    int* esrc     = ib + 770 + N + 2;         // E
    uint2* P      = (uint2*)Xf;               // E pairs (12.8MB) overlay dead Xf
    __hip_bfloat16* Th = Qh;                  // N*256 bf16 overlay (Qh+Kh dead)

    const dim3 blk(256);
    const int  nb    = (N + 63) / 64;
    const int  chunk = (E + 255) / 256;       // edges per partition block

    // ---- weight cast+transpose ----
    WArgs wa;
    wa.src[0] = Wq; wa.src[1] = Wk; wa.src[2] = Wv; wa.src[3] = Wo; wa.src[4] = W1; wa.src[5] = W2;
    wa.dst[0] = Wqt; wa.dst[1] = Wkt; wa.dst[2] = Wvt; wa.dst[3] = Wot; wa.dst[4] = W1t; wa.dst[5] = W2t;
    wa.R[0] = wa.R[1] = wa.R[2] = wa.R[3] = 128; wa.R[4] = 128; wa.R[5] = 256;
    wa.C[0] = wa.C[1] = wa.C[2] = wa.C[3] = 128; wa.C[4] = 256; wa.C[5] = 128;
    cast_w<<<dim3(128, 6), blk, 0, stream>>>(wa);

    // ---- QKV (A = fp32 h, converted during LDS staging) ----
    gemm_mfma<128,true,false,false,false,false,true><<<dim3(nb, 3), blk, 0, stream>>>(
        h, 128, Wqt, 128, nullptr, nullptr, nullptr, nullptr,
        nullptr, Qh, 128, (size_t)16384, (size_t)N * 128, N);

    // ---- bucketed sort of edges by dst ----
    hipMemsetAsync(bCnt, 0, 256 * sizeof(int), stream);
    bucket_hist<<<dim3(256), blk, 0, stream>>>(dst, bCnt, E, chunk, NB);
    bucket_scan<<<dim3(1), blk, 0, stream>>>(bCnt, bBase, gCur, rowStart, N, E, NB);
    partition_kernel<<<dim3(256), blk, 0, stream>>>(src, dst, gCur, P, E, chunk, NB);
    bucket_scatter<<<dim3(NB), blk, 0, stream>>>(P, bBase, rowStart, esrc, N);

    // ---- aggregate (writes h_attn bf16 into Qh) ----
    aggregate_kernel<<<dim3((N + 3) / 4), blk, 0, stream>>>(Qh, Kh, Vh, esrc, rowStart, N);

    // ---- X = LN1(h + h_attn@Wo + bo): write fp32 Xf + bf16 Xh ----
    gemm_mfma<128,false,false,true,true,true,false><<<dim3(nb, 1), blk, 0, stream>>>(
        Qh, 128, Wot, 128, bo, h, ln1g, ln1b, Xf, Xh, 128, 0, 0, N);

    // ---- T = relu(X@W1 + b1) -> bf16 ----
    gemm_mfma<128,false,true,false,false,true,false><<<dim3(nb, 2), blk, 0, stream>>>(
        Xh, 128, W1t, 128, b1, nullptr, nullptr, nullptr, nullptr, Th, 256, 0, 0, N);

    // ---- out = LN2(Xf + T@W2 + b2) -> fp32 ----
    gemm_mfma<256,false,false,true,true,true,false><<<dim3(nb, 1), blk, 0, stream>>>(
        Th, 256, W2t, 256, b2, Xf, ln2g, ln2b, (float*)d_out, nullptr, 128, 0, 0, N);
}